// Round 16
// baseline (130.793 us; speedup 1.0000x reference)
//
#include <hip/hip_runtime.h>

#define N_NODES 100000
#define NEDGE   1600000
#define D       32

#define BSHIFT   8
#define BNODES   256                                  // nodes per bucket
#define NBUCKET  ((N_NODES + BNODES - 1) / BNODES)    // 391
#define NB_PAD   392
#define EPB      4096                                 // edges per block in bin pass
#define EPT      (EPB / 256)                          // 16 edges per thread
#define CBLK     ((NEDGE + EPB - 1) / EPB)            // 391
#define CAP      5120                                 // LDS sort capacity (bucket mean 4096, sd~64)

// ---------- Kernel C: bin edges, CONTIGUOUS write-out + run tables ----------
// packed: x = src | (dst_local << 17)   (src < 2^17, dst_local < 256), y = w bits
// Block blk LDS-sorts its 4096 edges by bucket and writes them back
// contiguously at e0 (zero write amplification). Run metadata goes to
// tblc/tblo[blk][bucket] (coalesced rows); bucket totals via fire-and-forget
// atomics. The scatter moves to build_csr's READ side (cheap direction).
__global__ __launch_bounds__(256) void bin_edges_kernel(
        const int* __restrict__ src, const int* __restrict__ dst,
        const float* __restrict__ w,
        int* __restrict__ total, int* __restrict__ tblc, int* __restrict__ tblo,
        int2* __restrict__ binned) {
    __shared__ int2 sorted[EPB];                 // 32 KB
    __shared__ int cnt[NB_PAD];                  // hist, then local cursor
    __shared__ int ndoff[NB_PAD];                // local exclusive scan
    __shared__ int partial[256];

    const int tid = threadIdx.x;
    const int blk = blockIdx.x;
    const int e0  = blk * EPB;
    const int tot_e = min(EPB, NEDGE - e0);

    for (int i = tid; i < NB_PAD; i += 256) cnt[i] = 0;
    __syncthreads();

    // Phase 1: histogram; keep dst in statically-indexed registers
    int myd[EPT];
    #pragma unroll
    for (int it = 0; it < EPT; ++it) {
        int e = e0 + it * 256 + tid;
        myd[it] = (e < NEDGE) ? dst[e] : -1;
        if (myd[it] >= 0) atomicAdd(&cnt[myd[it] >> BSHIFT], 1);
    }
    __syncthreads();

    // Phase 2: local scan over 392 buckets (2 per thread) + table rows + totals
    {
        int b0 = tid * 2;
        int c0 = 0, c1 = 0, s = 0;
        if (b0 < NB_PAD) { c0 = cnt[b0]; c1 = cnt[b0 + 1]; s = c0 + c1; }
        partial[tid] = s;
        __syncthreads();
        int v = s;
        for (int o = 1; o < 256; o <<= 1) {
            int t2 = (tid >= o) ? partial[tid - o] : 0;
            __syncthreads();
            partial[tid] += t2;
            __syncthreads();
        }
        int run = partial[tid] - v;
        if (b0 < NB_PAD) {
            ndoff[b0] = run;
            tblc[blk * NB_PAD + b0] = c0;
            tblo[blk * NB_PAD + b0] = run;
            if (c0 > 0) atomicAdd(&total[b0], c0);
            cnt[b0] = 0;
            run += c0;
            ndoff[b0 + 1] = run;
            tblc[blk * NB_PAD + b0 + 1] = c1;
            tblo[blk * NB_PAD + b0 + 1] = run;
            if (c1 > 0) atomicAdd(&total[b0 + 1], c1);
            cnt[b0 + 1] = 0;
            run += c1;
        }
    }
    __syncthreads();

    // Phase 3: scatter into LDS (coalesced src/w loads, random LDS writes)
    #pragma unroll
    for (int it = 0; it < EPT; ++it) {
        int d = myd[it];
        if (d >= 0) {
            int e = e0 + it * 256 + tid;
            int b = d >> BSHIFT;
            int r = atomicAdd(&cnt[b], 1);
            sorted[ndoff[b] + r] = make_int2(src[e] | ((d & (BNODES - 1)) << 17),
                                             __float_as_int(w[e]));
        }
    }
    __syncthreads();

    // Phase 4: CONTIGUOUS coalesced write-out at e0 (zero amplification)
    for (int i = tid; i < tot_e; i += 256)
        binned[e0 + i] = sorted[i];
}

// ---------- Kernel B: exclusive scan of 392 bucket totals (1 block, 512 thr) ----------
__global__ void bucket_scan_kernel(const int* __restrict__ total, int* __restrict__ base) {
    __shared__ int s[512];
    int tid = threadIdx.x;
    int v = (tid < NB_PAD) ? total[tid] : 0;
    s[tid] = v;
    __syncthreads();
    for (int o = 1; o < 512; o <<= 1) {
        int t = (tid >= o) ? s[tid - o] : 0;
        __syncthreads();
        s[tid] += t;
        __syncthreads();
    }
    if (tid < NB_PAD) base[tid] = s[tid] - v;
}

// ---------- Kernel D: per-bucket CSR build from scattered runs ----------
// Block b (512 threads): thread j walks run j (block j's bucket-b edges,
// located via table columns, L2-resident). Two walks: node histogram, then
// scatter into LDS sorted[]. Compact CSR slice written contiguously at base[b].
__global__ __launch_bounds__(512) void build_csr_kernel(
        const int* __restrict__ total, const int* __restrict__ base,
        const int* __restrict__ tblc, const int* __restrict__ tblo,
        const int2* __restrict__ binned,
        int2* __restrict__ csr, int* __restrict__ offv, int* __restrict__ deg) {
    __shared__ int2 sorted[CAP];                 // 40 KB
    __shared__ int ndcnt[BNODES];
    __shared__ int ndoff[BNODES];

    const int b = blockIdx.x;
    const int tid = threadIdx.x;

    if (tid < BNODES) ndcnt[tid] = 0;
    int rl = 0, ro = 0;
    if (tid < CBLK) { rl = tblc[tid * NB_PAD + b]; ro = tblo[tid * NB_PAD + b]; }
    const int s0 = tid * EPB + ro;
    __syncthreads();

    // pass 1: node histogram over my run
    for (int i = 0; i < rl; ++i) {
        int2 p = binned[s0 + i];
        atomicAdd(&ndcnt[(p.x >> 17) & (BNODES - 1)], 1);
    }
    __syncthreads();

    // exclusive scan of 256 node counts (guarded; 512-thread block)
    int v = (tid < BNODES) ? ndcnt[tid] : 0;
    if (tid < BNODES) ndoff[tid] = v;
    __syncthreads();
    for (int o = 1; o < BNODES; o <<= 1) {
        int t = (tid < BNODES && tid >= o) ? ndoff[tid - o] : 0;
        __syncthreads();
        if (tid < BNODES) ndoff[tid] += t;
        __syncthreads();
    }
    if (tid < BNODES) {
        int incl = ndoff[tid];
        ndoff[tid] = incl - v;       // exclusive
        int node = b * BNODES + tid;
        if (node < N_NODES) {
            offv[node] = base[b] + incl - v;
            deg[node]  = v;
        }
        ndcnt[tid] = 0;              // reuse as cursor
    }
    __syncthreads();

    // pass 2: scatter my run into node-sorted LDS
    for (int i = 0; i < rl; ++i) {
        int2 p = binned[s0 + i];
        int dl = (p.x >> 17) & (BNODES - 1);
        int r = atomicAdd(&ndcnt[dl], 1);
        int loc = ndoff[dl] + r;
        if (loc < CAP) sorted[loc] = make_int2(p.x & 0x1FFFF, p.y);
    }
    __syncthreads();

    // compact coalesced write-out at base[b]
    const int totb = min(total[b], CAP);
    const int bb = base[b];
    for (int i = tid; i < totb; i += 512)
        csr[bb + i] = sorted[i];
}

// ---------- gather SpMM (no atomics, register acc, 4-way unrolled) ----------
// 8 threads per node; each owns a float4 slice of the 32-wide feature row.
__global__ void spmm_gather_kernel(const int* __restrict__ off, const int* __restrict__ deg,
                                   const int2* __restrict__ csr_sw,
                                   const float* __restrict__ x, float* __restrict__ out) {
    int gid = blockIdx.x * blockDim.x + threadIdx.x;
    if (gid >= N_NODES * 8) return;
    int node = gid >> 3;
    int c    = gid & 7;
    int start = off[node];
    int len   = deg[node];
    float4 acc = {0.f, 0.f, 0.f, 0.f};
    int k = 0;
    for (; k + 4 <= len; k += 4) {
        int2 sw0 = csr_sw[start + k];
        int2 sw1 = csr_sw[start + k + 1];
        int2 sw2 = csr_sw[start + k + 2];
        int2 sw3 = csr_sw[start + k + 3];
        const float4 xv0 = *reinterpret_cast<const float4*>(&x[(long)sw0.x * D + c * 4]);
        const float4 xv1 = *reinterpret_cast<const float4*>(&x[(long)sw1.x * D + c * 4]);
        const float4 xv2 = *reinterpret_cast<const float4*>(&x[(long)sw2.x * D + c * 4]);
        const float4 xv3 = *reinterpret_cast<const float4*>(&x[(long)sw3.x * D + c * 4]);
        float w0 = __int_as_float(sw0.y), w1 = __int_as_float(sw1.y);
        float w2 = __int_as_float(sw2.y), w3 = __int_as_float(sw3.y);
        acc.x += w0 * xv0.x; acc.y += w0 * xv0.y; acc.z += w0 * xv0.z; acc.w += w0 * xv0.w;
        acc.x += w1 * xv1.x; acc.y += w1 * xv1.y; acc.z += w1 * xv1.z; acc.w += w1 * xv1.w;
        acc.x += w2 * xv2.x; acc.y += w2 * xv2.y; acc.z += w2 * xv2.z; acc.w += w2 * xv2.w;
        acc.x += w3 * xv3.x; acc.y += w3 * xv3.y; acc.z += w3 * xv3.z; acc.w += w3 * xv3.w;
    }
    for (; k < len; ++k) {
        int2 sw = csr_sw[start + k];
        const float4 xv = *reinterpret_cast<const float4*>(&x[(long)sw.x * D + c * 4]);
        float wt = __int_as_float(sw.y);
        acc.x += wt * xv.x; acc.y += wt * xv.y; acc.z += wt * xv.z; acc.w += wt * xv.w;
    }
    *reinterpret_cast<float4*>(&out[(long)node * D + c * 4]) = acc;
}

// ---------- fallback (atomic scatter) if ws too small ----------
__global__ void spmm_scatter_kernel(const int* __restrict__ src, const int* __restrict__ dst,
                                    const float* __restrict__ w, const float* __restrict__ x,
                                    float* __restrict__ out) {
    long gid = (long)blockIdx.x * blockDim.x + threadIdx.x;
    if (gid >= (long)NEDGE * 8) return;
    int e = (int)(gid >> 3);
    int c = (int)(gid & 7);
    int s = src[e], d = dst[e];
    float wt = w[e];
    const float4 xv = *reinterpret_cast<const float4*>(&x[(long)s * D + c * 4]);
    float* o = &out[(long)d * D + c * 4];
    atomicAdd(o + 0, wt * xv.x);
    atomicAdd(o + 1, wt * xv.y);
    atomicAdd(o + 2, wt * xv.z);
    atomicAdd(o + 3, wt * xv.w);
}

extern "C" void kernel_launch(void* const* d_in, const int* in_sizes, int n_in,
                              void* d_out, int out_size, void* d_ws, size_t ws_size,
                              hipStream_t stream) {
    const float* x    = (const float*)d_in[0];
    const int*   esrc = (const int*)d_in[1];
    const int*   edst = (const int*)d_in[2];
    const float* ew   = (const float*)d_in[3];
    float* out = (float*)d_out;

    char* ws = (char*)d_ws;
    const size_t y_bytes   = (size_t)N_NODES * D * sizeof(float);         // 12.8 MB
    const size_t bin_sz    = (size_t)CBLK * EPB * sizeof(int2);           // 12.8 MB
    const size_t csr_sz    = (size_t)NEDGE * sizeof(int2);                // 12.8 MB
    const size_t n_ints    = (size_t)N_NODES * sizeof(int);               // 400 KB
    const size_t b_ints    = (size_t)NB_PAD * sizeof(int);                // 1.57 KB
    const size_t t_ints    = (size_t)CBLK * NB_PAD * sizeof(int);         // 613 KB

    size_t o = 0;
    float* y      = (float*)(ws + o); o += y_bytes;
    int2*  binned = (int2*) (ws + o); o += bin_sz;
    int2*  csr    = (int2*) (ws + o); o += csr_sz;
    int*   off    = (int*)  (ws + o); o += n_ints;
    int*   deg    = (int*)  (ws + o); o += n_ints;
    int*   total  = (int*)  (ws + o); o += b_ints;
    int*   base   = (int*)  (ws + o); o += b_ints;
    int*   tblc   = (int*)  (ws + o); o += t_ints;
    int*   tblo   = (int*)  (ws + o); o += t_ints;

    if (ws_size < o) {
        hipMemsetAsync(y, 0, y_bytes, stream);
        hipMemsetAsync(out, 0, y_bytes, stream);
        const long tot = (long)NEDGE * 8;
        const int blocks = (int)((tot + 255) / 256);
        spmm_scatter_kernel<<<blocks, 256, 0, stream>>>(esrc, edst, ew, x, y);
        spmm_scatter_kernel<<<blocks, 256, 0, stream>>>(esrc, edst, ew, y, out);
        return;
    }

    hipMemsetAsync(total, 0, b_ints, stream);
    bin_edges_kernel<<<CBLK, 256, 0, stream>>>(esrc, edst, ew, total, tblc, tblo, binned);
    bucket_scan_kernel<<<1, 512, 0, stream>>>(total, base);
    build_csr_kernel<<<NBUCKET, 512, 0, stream>>>(total, base, tblc, tblo, binned,
                                                  csr, off, deg);

    const int gblocks = (N_NODES * 8 + 255) / 256;
    spmm_gather_kernel<<<gblocks, 256, 0, stream>>>(off, deg, csr, x, y);
    spmm_gather_kernel<<<gblocks, 256, 0, stream>>>(off, deg, csr, y, out);
}

// Round 17
// 112.384 us; speedup vs baseline: 1.1638x; 1.1638x over previous
//
#include <hip/hip_runtime.h>

#define N_NODES 100000
#define NEDGE   1600000
#define D       32

#define BSHIFT   8
#define BNODES   256                                  // nodes per bucket
#define NBUCKET  ((N_NODES + BNODES - 1) / BNODES)    // 391
#define NB_PAD   392
#define EPB      4096                                 // edges per block in bin pass
#define EPT      (EPB / 256)                          // 16 edges per thread
#define CBLK     ((NEDGE + EPB - 1) / EPB)            // 391
#define CAP      5120                                 // arena slots per bucket (mean 4096, sd~64 -> 16 sigma)

// ---------- Kernel C: bin edges into fixed arenas, coalesced write-out ----------
// packed: x = src | (dst_local << 17)   (src < 2^17, dst_local < 256), y = w bits
// cur[] is RELATIVE (memset-0 seeded); arena base b*CAP added at use.
__global__ __launch_bounds__(256) void bin_edges_kernel(
        const int* __restrict__ src, const int* __restrict__ dst,
        const float* __restrict__ w,
        int* __restrict__ bucket_cur, int2* __restrict__ binned) {
    __shared__ int2 sorted[EPB];                 // 32 KB
    __shared__ unsigned short bucketOf[EPB];     //  8 KB
    __shared__ int cnt[NB_PAD];                  // hist, then local cursor
    __shared__ int ndoff[NB_PAD];                // local exclusive scan
    __shared__ int delta[NB_PAD];                // global_base - local_base
    __shared__ int partial[256];

    const int tid = threadIdx.x;
    const int e0  = blockIdx.x * EPB;
    const int total = min(EPB, NEDGE - e0);

    for (int i = tid; i < NB_PAD; i += 256) cnt[i] = 0;
    __syncthreads();

    // Phase 1: histogram; keep dst in statically-indexed registers
    int myd[EPT];
    #pragma unroll
    for (int it = 0; it < EPT; ++it) {
        int e = e0 + it * 256 + tid;
        myd[it] = (e < NEDGE) ? dst[e] : -1;
        if (myd[it] >= 0) atomicAdd(&cnt[myd[it] >> BSHIFT], 1);
    }
    __syncthreads();

    // Phase 2: local scan over 392 buckets (2 per thread) + global run claim
    {
        int b0 = tid * 2;
        int c0 = 0, c1 = 0, s = 0;
        if (b0 < NB_PAD) { c0 = cnt[b0]; c1 = cnt[b0 + 1]; s = c0 + c1; }
        partial[tid] = s;
        __syncthreads();
        int v = s;
        for (int o = 1; o < 256; o <<= 1) {
            int t2 = (tid >= o) ? partial[tid - o] : 0;
            __syncthreads();
            partial[tid] += t2;
            __syncthreads();
        }
        int run = partial[tid] - v;
        if (b0 < NB_PAD) {
            ndoff[b0] = run;
            if (c0 > 0) delta[b0] = b0 * CAP + atomicAdd(&bucket_cur[b0], c0) - run;
            cnt[b0] = 0;
            run += c0;
            ndoff[b0 + 1] = run;
            if (c1 > 0) delta[b0 + 1] = (b0 + 1) * CAP + atomicAdd(&bucket_cur[b0 + 1], c1) - run;
            cnt[b0 + 1] = 0;
            run += c1;
        }
    }
    __syncthreads();

    // Phase 3: scatter into LDS (coalesced src/w loads, random LDS writes)
    #pragma unroll
    for (int it = 0; it < EPT; ++it) {
        int d = myd[it];
        if (d >= 0) {
            int e = e0 + it * 256 + tid;
            int b = d >> BSHIFT;
            int r = atomicAdd(&cnt[b], 1);
            int loc = ndoff[b] + r;
            sorted[loc]   = make_int2(src[e] | ((d & (BNODES - 1)) << 17),
                                      __float_as_int(w[e]));
            bucketOf[loc] = (unsigned short)b;
        }
    }
    __syncthreads();

    // Phase 4: coalesced write-out (consecutive slots -> consecutive gaddr per run)
    for (int i = tid; i < total; i += 256) {
        int2 v = sorted[i];
        int  b = bucketOf[i];
        binned[delta[b] + i] = v;
    }
}

// ---------- Kernel D: per-bucket CSR slice node-sort, IN PLACE ----------
// Block b owns binned[b*CAP, b*CAP+cnt) exclusively. Slice is read twice from
// global (L2-hot) to keep LDS at ~42KB (3 blocks/CU). LDS scatter then
// coalesced in-place rewrite.
__global__ __launch_bounds__(256) void build_csr_kernel(
        const int* __restrict__ bucket_cur,
        int2* __restrict__ binned, int* __restrict__ offv, int* __restrict__ deg) {
    __shared__ int2 sorted[CAP];                 // 40 KB
    __shared__ int ndcnt[BNODES];
    __shared__ int ndoff[BNODES];

    int b = blockIdx.x;
    int tid = threadIdx.x;
    int start = b * CAP;
    int cnt_b = min(bucket_cur[b], CAP);

    ndcnt[tid] = 0;
    __syncthreads();

    // node histogram (pass 1 over slice)
    for (int i = tid; i < cnt_b; i += 256)
        atomicAdd(&ndcnt[(binned[start + i].x >> 17) & (BNODES - 1)], 1);
    __syncthreads();

    // exclusive scan of 256 node counts (blockDim == BNODES == 256)
    int v = ndcnt[tid];
    ndoff[tid] = v;
    __syncthreads();
    for (int o = 1; o < BNODES; o <<= 1) {
        int t = (tid >= o) ? ndoff[tid - o] : 0;
        __syncthreads();
        ndoff[tid] += t;
        __syncthreads();
    }
    {
        int incl = ndoff[tid];
        __syncthreads();
        ndoff[tid] = incl - v;       // exclusive
        int node = b * BNODES + tid;
        if (node < N_NODES) {
            offv[node] = start + incl - v;
            deg[node]  = v;
        }
        ndcnt[tid] = 0;              // reuse as cursor
    }
    __syncthreads();

    // pass 2: scatter into LDS node-sorted, then coalesced in-place rewrite
    for (int i = tid; i < cnt_b; i += 256) {
        int2 p = binned[start + i];
        int dl = (p.x >> 17) & (BNODES - 1);
        int r = atomicAdd(&ndcnt[dl], 1);
        sorted[ndoff[dl] + r] = make_int2(p.x & 0x1FFFF, p.y);
    }
    __syncthreads();
    for (int i = tid; i < cnt_b; i += 256) binned[start + i] = sorted[i];
}

// ---------- gather SpMM (no atomics, register acc, 4-way unrolled) ----------
// 8 threads per node; each owns a float4 slice of the 32-wide feature row.
__global__ void spmm_gather_kernel(const int* __restrict__ off, const int* __restrict__ deg,
                                   const int2* __restrict__ csr_sw,
                                   const float* __restrict__ x, float* __restrict__ out) {
    int gid = blockIdx.x * blockDim.x + threadIdx.x;
    if (gid >= N_NODES * 8) return;
    int node = gid >> 3;
    int c    = gid & 7;
    int start = off[node];
    int len   = deg[node];
    float4 acc = {0.f, 0.f, 0.f, 0.f};
    int k = 0;
    for (; k + 4 <= len; k += 4) {
        int2 sw0 = csr_sw[start + k];
        int2 sw1 = csr_sw[start + k + 1];
        int2 sw2 = csr_sw[start + k + 2];
        int2 sw3 = csr_sw[start + k + 3];
        const float4 xv0 = *reinterpret_cast<const float4*>(&x[(long)sw0.x * D + c * 4]);
        const float4 xv1 = *reinterpret_cast<const float4*>(&x[(long)sw1.x * D + c * 4]);
        const float4 xv2 = *reinterpret_cast<const float4*>(&x[(long)sw2.x * D + c * 4]);
        const float4 xv3 = *reinterpret_cast<const float4*>(&x[(long)sw3.x * D + c * 4]);
        float w0 = __int_as_float(sw0.y), w1 = __int_as_float(sw1.y);
        float w2 = __int_as_float(sw2.y), w3 = __int_as_float(sw3.y);
        acc.x += w0 * xv0.x; acc.y += w0 * xv0.y; acc.z += w0 * xv0.z; acc.w += w0 * xv0.w;
        acc.x += w1 * xv1.x; acc.y += w1 * xv1.y; acc.z += w1 * xv1.z; acc.w += w1 * xv1.w;
        acc.x += w2 * xv2.x; acc.y += w2 * xv2.y; acc.z += w2 * xv2.z; acc.w += w2 * xv2.w;
        acc.x += w3 * xv3.x; acc.y += w3 * xv3.y; acc.z += w3 * xv3.z; acc.w += w3 * xv3.w;
    }
    for (; k < len; ++k) {
        int2 sw = csr_sw[start + k];
        const float4 xv = *reinterpret_cast<const float4*>(&x[(long)sw.x * D + c * 4]);
        float wt = __int_as_float(sw.y);
        acc.x += wt * xv.x; acc.y += wt * xv.y; acc.z += wt * xv.z; acc.w += wt * xv.w;
    }
    *reinterpret_cast<float4*>(&out[(long)node * D + c * 4]) = acc;
}

// ---------- fallback (atomic scatter) if ws too small ----------
__global__ void spmm_scatter_kernel(const int* __restrict__ src, const int* __restrict__ dst,
                                    const float* __restrict__ w, const float* __restrict__ x,
                                    float* __restrict__ out) {
    long gid = (long)blockIdx.x * blockDim.x + threadIdx.x;
    if (gid >= (long)NEDGE * 8) return;
    int e = (int)(gid >> 3);
    int c = (int)(gid & 7);
    int s = src[e], d = dst[e];
    float wt = w[e];
    const float4 xv = *reinterpret_cast<const float4*>(&x[(long)s * D + c * 4]);
    float* o = &out[(long)d * D + c * 4];
    atomicAdd(o + 0, wt * xv.x);
    atomicAdd(o + 1, wt * xv.y);
    atomicAdd(o + 2, wt * xv.z);
    atomicAdd(o + 3, wt * xv.w);
}

extern "C" void kernel_launch(void* const* d_in, const int* in_sizes, int n_in,
                              void* d_out, int out_size, void* d_ws, size_t ws_size,
                              hipStream_t stream) {
    const float* x    = (const float*)d_in[0];
    const int*   esrc = (const int*)d_in[1];
    const int*   edst = (const int*)d_in[2];
    const float* ew   = (const float*)d_in[3];
    float* out = (float*)d_out;

    char* ws = (char*)d_ws;
    const size_t y_bytes   = (size_t)N_NODES * D * sizeof(float);     // 12.8 MB
    const size_t n_ints    = (size_t)N_NODES * sizeof(int);           // 400 KB
    const size_t b_ints    = (size_t)NB_PAD * sizeof(int);
    const size_t arena_sz  = (size_t)NBUCKET * CAP * sizeof(int2);    // 16.0 MB

    size_t o = 0;
    float* y          = (float*)(ws + o); o += y_bytes;
    int2*  binned     = (int2*) (ws + o); o += arena_sz;              // CSR built in place
    int*   off        = (int*)  (ws + o); o += n_ints;
    int*   deg        = (int*)  (ws + o); o += n_ints;
    int*   bucket_cur = (int*)  (ws + o); o += b_ints;

    if (ws_size < o) {
        hipMemsetAsync(y, 0, y_bytes, stream);
        hipMemsetAsync(out, 0, y_bytes, stream);
        const long total = (long)NEDGE * 8;
        const int blocks = (int)((total + 255) / 256);
        spmm_scatter_kernel<<<blocks, 256, 0, stream>>>(esrc, edst, ew, x, y);
        spmm_scatter_kernel<<<blocks, 256, 0, stream>>>(esrc, edst, ew, y, out);
        return;
    }

    hipMemsetAsync(bucket_cur, 0, b_ints, stream);   // relative cursors: memset replaces init kernel
    bin_edges_kernel<<<CBLK, 256, 0, stream>>>(esrc, edst, ew, bucket_cur, binned);
    build_csr_kernel<<<NBUCKET, 256, 0, stream>>>(bucket_cur, binned, off, deg);

    const int gblocks = (N_NODES * 8 + 255) / 256;
    spmm_gather_kernel<<<gblocks, 256, 0, stream>>>(off, deg, binned, x, y);
    spmm_gather_kernel<<<gblocks, 256, 0, stream>>>(off, deg, binned, y, out);
}